// Round 1
// baseline (2434.004 us; speedup 1.0000x reference)
//
#include <hip/hip_runtime.h>
#include <math.h>

#define NB    4
#define CDIM  256
#define NSEQ  2304          // 48*48
#define NHEAD 8
#define HD    32
#define SCALEF 0.17677669529663687f   // 32^-0.5
#define LOG2E  1.4426950408889634f

// ---------------------------------------------------------------------------
// Kernel 1: fused QKV projection.
// X: (B, C, N) feature-major input.  Wq: (C,256), Wkv: (C,512) row-major.
// P: (B, N, 768) = [Q(256) | K(256) | V(256)], column = h*32 + d.
// 64x64 output tile per block, 256 threads, 4x4 micro-tile, k-chunks of 16.
// ---------------------------------------------------------------------------
__global__ __launch_bounds__(256) void proj_qkv(
    const float* __restrict__ X, const float* __restrict__ Wq,
    const float* __restrict__ Wkv, float* __restrict__ P)
{
  __shared__ float As[16][64];
  __shared__ float Bs[16][64];
  const int b  = blockIdx.z;
  const int n0 = blockIdx.y * 64;
  const int j0 = blockIdx.x * 64;
  const int t  = threadIdx.x;
  const int tn = t & 15, tj = t >> 4;

  const float* Wsrc; int wld, jb;
  if (j0 < 256) { Wsrc = Wq;  wld = 256; jb = j0; }
  else          { Wsrc = Wkv; wld = 512; jb = j0 - 256; }

  const float* Xb = X + (size_t)b * CDIM * NSEQ;

  float acc[4][4];
#pragma unroll
  for (int i = 0; i < 4; ++i)
#pragma unroll
    for (int j = 0; j < 4; ++j) acc[i][j] = 0.f;

  const int akc = t >> 4;          // 0..15  (k row)
  const int ann = (t & 15) * 4;    // 0..60  (float4 col)

  for (int c0 = 0; c0 < CDIM; c0 += 16) {
    float4 av = *(const float4*)(Xb   + (size_t)(c0 + akc) * NSEQ + n0 + ann);
    float4 bv = *(const float4*)(Wsrc + (size_t)(c0 + akc) * wld  + jb + ann);
    *(float4*)&As[akc][ann] = av;
    *(float4*)&Bs[akc][ann] = bv;
    __syncthreads();
#pragma unroll
    for (int k = 0; k < 16; ++k) {
      float4 a = *(const float4*)&As[k][tn * 4];
      float4 w = *(const float4*)&Bs[k][tj * 4];
      float aa[4] = {a.x, a.y, a.z, a.w};
      float ww[4] = {w.x, w.y, w.z, w.w};
#pragma unroll
      for (int i = 0; i < 4; ++i)
#pragma unroll
        for (int j = 0; j < 4; ++j) acc[i][j] = fmaf(aa[i], ww[j], acc[i][j]);
    }
    __syncthreads();
  }

  float* Pd = P + ((size_t)b * NSEQ + n0 + tn * 4) * 768 + j0 + tj * 4;
#pragma unroll
  for (int i = 0; i < 4; ++i) {
    float4 v = make_float4(acc[i][0], acc[i][1], acc[i][2], acc[i][3]);
    *(float4*)(Pd + (size_t)i * 768) = v;
  }
}

// ---------------------------------------------------------------------------
// Kernel 2: flash-style cross-attention, fp32, online softmax.
// One wave (64 threads) per block, 2 query rows per thread (128 rows/block).
// K/V tiles of 64 rows staged in LDS; all lanes read the same K/V row per
// inner step -> LDS broadcast, no bank conflicts.
// PQ provides Q (cols 0..255); PKV provides K (256..511) and V (512..767).
// A: (B, N, 256) attention output in sequence layout.
// ---------------------------------------------------------------------------
template <bool USE_U>
__global__ __launch_bounds__(64, 2) void attn_kernel(
    const float* __restrict__ PQ, const float* __restrict__ PKV,
    const float* __restrict__ U, float* __restrict__ A)
{
  __shared__ float Ks[64][HD];
  __shared__ float Vs[64][HD];
  const int bh = blockIdx.y, b = bh >> 3, h = bh & 7;
  const int t  = threadIdx.x;
  const int n0 = blockIdx.x * 128;
  const int n1 = n0 + t, n2 = n0 + 64 + t;

  const float* Pq = PQ + (size_t)b * NSEQ * 768;
  const float* Pk = PKV + (size_t)b * NSEQ * 768 + 256 + h * HD;

  float w1 = 1.f, w2 = 1.f;
  if (USE_U) {
    w1 = 1.f / (U[b * NSEQ + n1] + 1e-6f);
    w2 = 1.f / (U[b * NSEQ + n2] + 1e-6f);
  }
  const float qs1 = SCALEF * LOG2E * w1;
  const float qs2 = SCALEF * LOG2E * w2;

  float q1[HD], q2[HD];
#pragma unroll
  for (int i = 0; i < 8; ++i) {
    float4 v = *(const float4*)(Pq + (size_t)n1 * 768 + h * HD + i * 4);
    q1[4*i+0] = v.x * qs1; q1[4*i+1] = v.y * qs1;
    q1[4*i+2] = v.z * qs1; q1[4*i+3] = v.w * qs1;
    float4 u = *(const float4*)(Pq + (size_t)n2 * 768 + h * HD + i * 4);
    q2[4*i+0] = u.x * qs2; q2[4*i+1] = u.y * qs2;
    q2[4*i+2] = u.z * qs2; q2[4*i+3] = u.w * qs2;
  }

  float m1 = -1e30f, m2 = -1e30f, l1 = 0.f, l2 = 0.f;
  float acc1[HD], acc2[HD];
#pragma unroll
  for (int d = 0; d < HD; ++d) { acc1[d] = 0.f; acc2[d] = 0.f; }

  for (int m0 = 0; m0 < NSEQ; m0 += 64) {
    __syncthreads();
#pragma unroll
    for (int i = 0; i < 8; ++i) {
      int f = t + i * 64;              // 0..511
      int row = f >> 3, c4 = (f & 7) * 4;
      const float* src = Pk + (size_t)(m0 + row) * 768 + c4;
      *(float4*)&Ks[row][c4] = *(const float4*)(src);
      *(float4*)&Vs[row][c4] = *(const float4*)(src + 256);
    }
    __syncthreads();

    for (int mm = 0; mm < 64; ++mm) {
      float s1 = 0.f, s2 = 0.f;
#pragma unroll
      for (int d = 0; d < HD; ++d) {
        float kk = Ks[mm][d];
        s1 = fmaf(q1[d], kk, s1);
        s2 = fmaf(q2[d], kk, s2);
      }
      if (s1 > m1) {
        float al = exp2f(m1 - s1); m1 = s1; l1 *= al;
#pragma unroll
        for (int d = 0; d < HD; ++d) acc1[d] *= al;
      }
      if (s2 > m2) {
        float al = exp2f(m2 - s2); m2 = s2; l2 *= al;
#pragma unroll
        for (int d = 0; d < HD; ++d) acc2[d] *= al;
      }
      float p1 = exp2f(s1 - m1), p2 = exp2f(s2 - m2);
      l1 += p1; l2 += p2;
#pragma unroll
      for (int d = 0; d < HD; ++d) {
        float vv = Vs[mm][d];
        acc1[d] = fmaf(p1, vv, acc1[d]);
        acc2[d] = fmaf(p2, vv, acc2[d]);
      }
    }
  }

  const float i1 = 1.f / l1, i2 = 1.f / l2;
  float* d1 = A + ((size_t)b * NSEQ + n1) * CDIM + h * HD;
  float* d2 = A + ((size_t)b * NSEQ + n2) * CDIM + h * HD;
#pragma unroll
  for (int i = 0; i < 8; ++i) {
    *(float4*)(d1 + 4*i) = make_float4(acc1[4*i]*i1, acc1[4*i+1]*i1,
                                       acc1[4*i+2]*i1, acc1[4*i+3]*i1);
    *(float4*)(d2 + 4*i) = make_float4(acc2[4*i]*i2, acc2[4*i+1]*i2,
                                       acc2[4*i+2]*i2, acc2[4*i+3]*i2);
  }
}

// ---------------------------------------------------------------------------
// Kernel 3: output projection + bias, writing (B, C, N) layout directly.
// A: (B, N, 256); Wp: (256,256); O[b, j, n] = sum_c A[b,n,c]*Wp[c,j] + bp[j].
// A-tile is transposed into LDS -> pad leading dim to 68 to avoid 16-way
// bank conflicts on the scatter write.
// ---------------------------------------------------------------------------
__global__ __launch_bounds__(256) void proj_out(
    const float* __restrict__ A, const float* __restrict__ Wp,
    const float* __restrict__ bp, float* __restrict__ O)
{
  __shared__ float As[16][68];
  __shared__ float Bs[16][64];
  const int b  = blockIdx.z;
  const int n0 = blockIdx.y * 64;
  const int j0 = blockIdx.x * 64;
  const int t  = threadIdx.x;
  const int tn = t & 15, tj = t >> 4;

  float acc[4][4];
#pragma unroll
  for (int i = 0; i < 4; ++i)
#pragma unroll
    for (int j = 0; j < 4; ++j) acc[i][j] = 0.f;

  const int ann = t >> 2;            // 0..63  (n within tile)
  const int akc = (t & 3) * 4;       // 0,4,8,12 (c chunk)
  const int bkc = t >> 4;            // 0..15
  const int bjj = (t & 15) * 4;      // 0..60

  for (int c0 = 0; c0 < CDIM; c0 += 16) {
    float4 av = *(const float4*)(A + ((size_t)b * NSEQ + n0 + ann) * CDIM + c0 + akc);
    float4 bv = *(const float4*)(Wp + (size_t)(c0 + bkc) * CDIM + j0 + bjj);
    As[akc + 0][ann] = av.x;
    As[akc + 1][ann] = av.y;
    As[akc + 2][ann] = av.z;
    As[akc + 3][ann] = av.w;
    *(float4*)&Bs[bkc][bjj] = bv;
    __syncthreads();
#pragma unroll
    for (int k = 0; k < 16; ++k) {
      float4 a = *(const float4*)&As[k][tn * 4];
      float4 w = *(const float4*)&Bs[k][tj * 4];
      float aa[4] = {a.x, a.y, a.z, a.w};
      float ww[4] = {w.x, w.y, w.z, w.w};
#pragma unroll
      for (int i = 0; i < 4; ++i)
#pragma unroll
        for (int j = 0; j < 4; ++j) acc[i][j] = fmaf(aa[i], ww[j], acc[i][j]);
    }
    __syncthreads();
  }

  float* Ob = O + (size_t)b * CDIM * NSEQ;
#pragma unroll
  for (int ji = 0; ji < 4; ++ji) {
    int j = j0 + tj * 4 + ji;
    float bias = bp[j];
    float4 v = make_float4(acc[0][ji] + bias, acc[1][ji] + bias,
                           acc[2][ji] + bias, acc[3][ji] + bias);
    *(float4*)(Ob + (size_t)j * NSEQ + n0 + tn * 4) = v;
  }
}

// ---------------------------------------------------------------------------
extern "C" void kernel_launch(void* const* d_in, const int* in_sizes, int n_in,
                              void* d_out, int out_size, void* d_ws, size_t ws_size,
                              hipStream_t stream) {
  const float* img     = (const float*)d_in[0];
  const float* rad     = (const float*)d_in[1];
  const float* U       = (const float*)d_in[2];
  const float* Wq_img  = (const float*)d_in[3];
  const float* Wkv_rad = (const float*)d_in[4];
  const float* Wq_rad  = (const float*)d_in[5];
  const float* Wkv_img = (const float*)d_in[6];
  const float* Wp_img  = (const float*)d_in[7];
  const float* bp_img  = (const float*)d_in[8];
  const float* Wp_rad  = (const float*)d_in[9];
  const float* bp_rad  = (const float*)d_in[10];
  float* out = (float*)d_out;

  // Workspace: P_img | P_rad : (B,N,768) each; A_img | A_rad : (B,N,256) each.
  float* P_img = (float*)d_ws;
  float* P_rad = P_img + (size_t)NB * NSEQ * 768;
  float* A_img = P_rad + (size_t)NB * NSEQ * 768;
  float* A_rad = A_img + (size_t)NB * NSEQ * CDIM;

  // P_img = [img@Wq_img | img@Wkv_img(K|V)] ; P_rad likewise for radar.
  dim3 gp(12, 36, NB);
  proj_qkv<<<gp, 256, 0, stream>>>(img, Wq_img, Wkv_img, P_img);
  proj_qkv<<<gp, 256, 0, stream>>>(rad, Wq_rad, Wkv_rad, P_rad);

  // img branch: Q from img, K/V from radar, uncertainty weighting.
  // radar branch: Q from radar, K/V from img, no weighting.
  dim3 ga(NSEQ / 128, NB * NHEAD);
  attn_kernel<true ><<<ga, 64, 0, stream>>>(P_img, P_rad, U, A_img);
  attn_kernel<false><<<ga, 64, 0, stream>>>(P_rad, P_img, nullptr, A_rad);

  dim3 go(4, 36, NB);
  proj_out<<<go, 256, 0, stream>>>(A_img, Wp_img, bp_img, out);
  proj_out<<<go, 256, 0, stream>>>(A_rad, Wp_rad, bp_rad,
                                   out + (size_t)NB * CDIM * NSEQ);
}

// Round 3
// 473.241 us; speedup vs baseline: 5.1433x; 5.1433x over previous
//
#include <hip/hip_runtime.h>
#include <math.h>

#define NB    4
#define CDIM  256
#define NSEQ  2304          // 48*48
#define NHEAD 8
#define HD    32
// SCALE * LOG2E folded into Q at projection time
#define QSCALE (0.17677669529663687f * 1.4426950408889634f)
#define INV2048 4.8828125e-4f

typedef _Float16 f16;
typedef _Float16 f16x8 __attribute__((ext_vector_type(8)));
typedef _Float16 f16x4 __attribute__((ext_vector_type(4)));
typedef float    f32x4 __attribute__((ext_vector_type(4)));

// ---------------------------------------------------------------------------
// Kernel 1: fused QKV projection, both modalities (z = mod*4+b), emitting
// f16 hi/lo splits directly (conversion done once, not per-attention-block).
//   Qh/Ql: [mod][b][n][256]  (QSCALE folded in; lo = (v-hi)*2048)
//   Kh/Kl: [mod][b][key][256]
//   Vt:    [mod][b][c=h*32+d][key]   (transposed, single f16)
// 64x64 tile per block, 256 threads, 4x4 micro-tile.
// ---------------------------------------------------------------------------
__global__ __launch_bounds__(256) void proj_qkv(
    const float* __restrict__ X0, const float* __restrict__ X1,
    const float* __restrict__ Wq0, const float* __restrict__ Wkv0,
    const float* __restrict__ Wq1, const float* __restrict__ Wkv1,
    f16* __restrict__ Qh, f16* __restrict__ Ql,
    f16* __restrict__ Kh, f16* __restrict__ Kl, f16* __restrict__ Vt)
{
  __shared__ float As[16][64];
  __shared__ float Bs[16][64];
  const int zz = blockIdx.z;
  const int mod = zz >> 2, b = zz & 3;
  const int n0 = blockIdx.y * 64;
  const int j0 = blockIdx.x * 64;
  const int t  = threadIdx.x;
  const int tn = t & 15, tj = t >> 4;
  const int bn = mod * NB + b;

  const float* X   = mod ? X1  : X0;
  const float* Wq  = mod ? Wq1 : Wq0;
  const float* Wkv = mod ? Wkv1 : Wkv0;

  const float* Wsrc; int wld, jb;
  if (j0 < 256) { Wsrc = Wq;  wld = 256; jb = j0; }
  else          { Wsrc = Wkv; wld = 512; jb = j0 - 256; }

  const float* Xb = X + (size_t)b * CDIM * NSEQ;

  float acc[4][4];
#pragma unroll
  for (int i = 0; i < 4; ++i)
#pragma unroll
    for (int j = 0; j < 4; ++j) acc[i][j] = 0.f;

  const int akc = t >> 4;          // 0..15  (k row)
  const int ann = (t & 15) * 4;    // 0..60  (float4 col)

  for (int c0 = 0; c0 < CDIM; c0 += 16) {
    float4 av = *(const float4*)(Xb   + (size_t)(c0 + akc) * NSEQ + n0 + ann);
    float4 bv = *(const float4*)(Wsrc + (size_t)(c0 + akc) * wld  + jb + ann);
    *(float4*)&As[akc][ann] = av;
    *(float4*)&Bs[akc][ann] = bv;
    __syncthreads();
#pragma unroll
    for (int k = 0; k < 16; ++k) {
      float4 a = *(const float4*)&As[k][tn * 4];
      float4 w = *(const float4*)&Bs[k][tj * 4];
      float aa[4] = {a.x, a.y, a.z, a.w};
      float ww[4] = {w.x, w.y, w.z, w.w};
#pragma unroll
      for (int i = 0; i < 4; ++i)
#pragma unroll
        for (int j = 0; j < 4; ++j) acc[i][j] = fmaf(aa[i], ww[j], acc[i][j]);
    }
    __syncthreads();
  }

  if (j0 < 256) {
    // Q: scale folded, hi/lo split, row-major [n][256]
#pragma unroll
    for (int i = 0; i < 4; ++i) {
      int n = n0 + tn * 4 + i;
      f16x4 hv, lv;
#pragma unroll
      for (int j = 0; j < 4; ++j) {
        float v = acc[i][j] * QSCALE;
        f16 hh = (f16)v;
        hv[j] = hh;
        lv[j] = (f16)((v - (float)hh) * 2048.0f);
      }
      size_t off = ((size_t)bn * NSEQ + n) * 256 + j0 + tj * 4;
      *(f16x4*)(Qh + off) = hv;
      *(f16x4*)(Ql + off) = lv;
    }
  } else if (j0 < 512) {
    // K: hi/lo split, row-major [key][256]
#pragma unroll
    for (int i = 0; i < 4; ++i) {
      int n = n0 + tn * 4 + i;
      f16x4 hv, lv;
#pragma unroll
      for (int j = 0; j < 4; ++j) {
        float v = acc[i][j];
        f16 hh = (f16)v;
        hv[j] = hh;
        lv[j] = (f16)((v - (float)hh) * 2048.0f);
      }
      size_t off = ((size_t)bn * NSEQ + n) * 256 + (j0 - 256) + tj * 4;
      *(f16x4*)(Kh + off) = hv;
      *(f16x4*)(Kl + off) = lv;
    }
  } else {
    // V: transposed [c][key], single f16 (pack 4 consecutive n per column)
#pragma unroll
    for (int j = 0; j < 4; ++j) {
      int jv = (j0 - 512) + tj * 4 + j;
      f16x4 hv;
#pragma unroll
      for (int i = 0; i < 4; ++i) hv[i] = (f16)acc[i][j];
      size_t off = ((size_t)bn * 256 + jv) * NSEQ + n0 + tn * 4;
      *(f16x4*)(Vt + off) = hv;
    }
  }
}

// ---------------------------------------------------------------------------
// Kernel 2: MFMA flash attention, S^T formulation.
// Block = 256 threads (4 waves); wave w owns q-group [qtile*64 + w*16, +16);
// all waves iterate the same 64-key chunks staged in shared LDS.
// S^T tile (16k x 16q) = K(16x32) x Q^T(32x16) via mfma_f32_16x16x32_f16,
// hi/lo split: s = (main + cross/2048) * uw.  C-layout: col=lane&15=q,
// row=quad*4+reg=key  ->  softmax state (m,l) is per-lane, rescale is local.
// P^T (C-layout) -> B-operand via in-wave shuffles; V^T A-frags from LDS.
// out^T accumulates in C-layout (col=q), normalized + scattered to A fp32.
// branch 0: Q=img, K/V=radar, uncertainty weight; branch 1: Q=radar, K/V=img.
// ---------------------------------------------------------------------------
__global__ __launch_bounds__(256) void attn_mfma(
    const f16* __restrict__ Qh, const f16* __restrict__ Ql,
    const f16* __restrict__ Kh, const f16* __restrict__ Kl,
    const f16* __restrict__ Vt, const float* __restrict__ U,
    float* __restrict__ A)
{
  __shared__ f16 KhS[64][40];   // 64 keys x 32 d, pad 32->40 (2-way only)
  __shared__ f16 KlS[64][40];
  __shared__ f16 VtS[32][72];   // 32 d x 64 keys, pad 64->72

  const int branch = blockIdx.z;
  const int bh = blockIdx.y, b = bh >> 3, h = bh & 7;
  const int tid = threadIdx.x;
  const int wave = tid >> 6, lane = tid & 63;
  const int col = lane & 15, quad = lane >> 4;
  const int qrow = blockIdx.x * 64 + wave * 16 + col;

  const int qmod = branch;          // branch0: Q=img(mod0); branch1: Q=radar
  const int kmod = 1 - branch;
  const size_t qoff = ((size_t)(qmod * NB + b) * NSEQ + qrow) * 256 + h * HD;
  const size_t kbase = (size_t)(kmod * NB + b) * NSEQ;
  const size_t vbase = (size_t)(kmod * NB + b) * 256;

  // Q fragments (B operand): B[k=d=quad*8+j][n=q=col]
  const f16x8 bqh = *(const f16x8*)(Qh + qoff + quad * 8);
  const f16x8 bql = *(const f16x8*)(Ql + qoff + quad * 8);

  float uw = 1.0f;
  if (branch == 0) uw = 1.0f / (U[b * NSEQ + qrow] + 1e-6f);

  float m = -1e30f, l = 0.f;
  f32x4 oc0 = {0.f, 0.f, 0.f, 0.f};   // out^T d 0..15
  f32x4 oc1 = {0.f, 0.f, 0.f, 0.f};   // out^T d 16..31
  const f32x4 z4 = {0.f, 0.f, 0.f, 0.f};

  for (int k0 = 0; k0 < NSEQ; k0 += 64) {
    __syncthreads();
    {
      // stage K hi/lo (64 rows x 64B) and V^T (32 rows x 128B); 256 threads
      int row = tid >> 2, seg = tid & 3;
      size_t g = (kbase + k0 + row) * 256 + h * HD + seg * 8;
      *(f16x8*)&KhS[row][seg * 8] = *(const f16x8*)(Kh + g);
      *(f16x8*)&KlS[row][seg * 8] = *(const f16x8*)(Kl + g);
      int vrow = tid >> 3, vseg = tid & 7;
      size_t gv = (vbase + h * HD + vrow) * NSEQ + k0 + vseg * 8;
      *(f16x8*)&VtS[vrow][vseg * 8] = *(const f16x8*)(Vt + gv);
    }
    __syncthreads();

    // ---- S^T: 4 tiles of 16 keys; lane holds p[t*4+r] = key 16t+4*quad+r
    float p[16];
    float cmax = -1e30f;
#pragma unroll
    for (int t = 0; t < 4; ++t) {
      f16x8 ah = *(const f16x8*)&KhS[t * 16 + col][quad * 8];
      f16x8 al = *(const f16x8*)&KlS[t * 16 + col][quad * 8];
      f32x4 mn = __builtin_amdgcn_mfma_f32_16x16x32_f16(ah, bqh, z4, 0, 0, 0);
      f32x4 cr = __builtin_amdgcn_mfma_f32_16x16x32_f16(ah, bql, z4, 0, 0, 0);
      cr = __builtin_amdgcn_mfma_f32_16x16x32_f16(al, bqh, cr, 0, 0, 0);
#pragma unroll
      for (int r = 0; r < 4; ++r) {
        float s = fmaf(cr[r], INV2048, mn[r]) * uw;
        p[t * 4 + r] = s;
        cmax = fmaxf(cmax, s);
      }
    }
    // column max/sum live on lanes {L, L^16, L^32, L^48}
    cmax = fmaxf(cmax, __shfl_xor(cmax, 16, 64));
    cmax = fmaxf(cmax, __shfl_xor(cmax, 32, 64));
    const float mnew = fmaxf(m, cmax);
    const float alpha = exp2f(m - mnew);
    m = mnew;
    float ls = 0.f;
#pragma unroll
    for (int i = 0; i < 16; ++i) { p[i] = exp2f(p[i] - mnew); ls += p[i]; }
    ls += __shfl_xor(ls, 16, 64);
    ls += __shfl_xor(ls, 32, 64);
    l = l * alpha + ls;
#pragma unroll
    for (int r = 0; r < 4; ++r) { oc0[r] *= alpha; oc1[r] *= alpha; }

    // ---- PV: out^T[d][q] += V^T(32d x 32k) * P^T(32k x 16q), 2 k-subchunks
#pragma unroll
    for (int s = 0; s < 2; ++s) {
      // B[k=32s+8*quad+j][q=col] from C-layout p[] via in-wave shuffles:
      // src tile = 2s + (quad>>1), src reg = j&3,
      // src lane = col + 32*(quad&1) + 16*(j>>2)
      f16x8 bp;
#pragma unroll
      for (int j = 0; j < 8; ++j) {
        int srcl = col + 32 * (quad & 1) + 16 * (j >> 2);
        float v0 = __shfl(p[(2 * s) * 4 + (j & 3)], srcl, 64);
        float v1 = __shfl(p[(2 * s + 1) * 4 + (j & 3)], srcl, 64);
        bp[j] = (f16)((quad >> 1) ? v1 : v0);
      }
      f16x8 av0 = *(const f16x8*)&VtS[col][s * 32 + quad * 8];
      f16x8 av1 = *(const f16x8*)&VtS[16 + col][s * 32 + quad * 8];
      oc0 = __builtin_amdgcn_mfma_f32_16x16x32_f16(av0, bp, oc0, 0, 0, 0);
      oc1 = __builtin_amdgcn_mfma_f32_16x16x32_f16(av1, bp, oc1, 0, 0, 0);
    }
  }

  const float inv = 1.0f / l;
  float* dst = A + (((size_t)(branch * NB + b) * NSEQ) + qrow) * CDIM + h * HD;
#pragma unroll
  for (int r = 0; r < 4; ++r) {
    dst[quad * 4 + r]      = oc0[r] * inv;
    dst[16 + quad * 4 + r] = oc1[r] * inv;
  }
}

// ---------------------------------------------------------------------------
// Kernel 3: output projection + bias, both modalities (z = mod*4+b), writing
// (B, C, N) layout directly.  A: (mod, B, N, 256); O[mod][b, j, n].
// ---------------------------------------------------------------------------
__global__ __launch_bounds__(256) void proj_out(
    const float* __restrict__ A, const float* __restrict__ Wp0,
    const float* __restrict__ bp0, const float* __restrict__ Wp1,
    const float* __restrict__ bp1, float* __restrict__ O)
{
  __shared__ float As[16][68];
  __shared__ float Bs[16][64];
  const int zz = blockIdx.z;
  const int mod = zz >> 2, b = zz & 3;
  const int n0 = blockIdx.y * 64;
  const int j0 = blockIdx.x * 64;
  const int t  = threadIdx.x;
  const int tn = t & 15, tj = t >> 4;

  const float* Wp = mod ? Wp1 : Wp0;
  const float* bp = mod ? bp1 : bp0;
  const float* Ab = A + (size_t)(mod * NB + b) * NSEQ * CDIM;

  float acc[4][4];
#pragma unroll
  for (int i = 0; i < 4; ++i)
#pragma unroll
    for (int j = 0; j < 4; ++j) acc[i][j] = 0.f;

  const int ann = t >> 2;            // 0..63  (n within tile)
  const int akc = (t & 3) * 4;       // 0,4,8,12 (c chunk)
  const int bkc = t >> 4;            // 0..15
  const int bjj = (t & 15) * 4;      // 0..60

  for (int c0 = 0; c0 < CDIM; c0 += 16) {
    float4 av = *(const float4*)(Ab + (size_t)(n0 + ann) * CDIM + c0 + akc);
    float4 bv = *(const float4*)(Wp + (size_t)(c0 + bkc) * CDIM + j0 + bjj);
    As[akc + 0][ann] = av.x;
    As[akc + 1][ann] = av.y;
    As[akc + 2][ann] = av.z;
    As[akc + 3][ann] = av.w;
    *(float4*)&Bs[bkc][bjj] = bv;
    __syncthreads();
#pragma unroll
    for (int k = 0; k < 16; ++k) {
      float4 a = *(const float4*)&As[k][tn * 4];
      float4 w = *(const float4*)&Bs[k][tj * 4];
      float aa[4] = {a.x, a.y, a.z, a.w};
      float ww[4] = {w.x, w.y, w.z, w.w};
#pragma unroll
      for (int i = 0; i < 4; ++i)
#pragma unroll
        for (int j = 0; j < 4; ++j) acc[i][j] = fmaf(aa[i], ww[j], acc[i][j]);
    }
    __syncthreads();
  }

  float* Ob = O + (size_t)(mod * NB + b) * CDIM * NSEQ;
#pragma unroll
  for (int ji = 0; ji < 4; ++ji) {
    int j = j0 + tj * 4 + ji;
    float bias = bp[j];
    float4 v = make_float4(acc[0][ji] + bias, acc[1][ji] + bias,
                           acc[2][ji] + bias, acc[3][ji] + bias);
    *(float4*)(Ob + (size_t)j * NSEQ + n0 + tn * 4) = v;
  }
}

// ---------------------------------------------------------------------------
extern "C" void kernel_launch(void* const* d_in, const int* in_sizes, int n_in,
                              void* d_out, int out_size, void* d_ws, size_t ws_size,
                              hipStream_t stream) {
  (void)in_sizes; (void)n_in; (void)out_size; (void)ws_size;
  const float* img     = (const float*)d_in[0];
  const float* rad     = (const float*)d_in[1];
  const float* U       = (const float*)d_in[2];
  const float* Wq_img  = (const float*)d_in[3];
  const float* Wkv_rad = (const float*)d_in[4];
  const float* Wq_rad  = (const float*)d_in[5];
  const float* Wkv_img = (const float*)d_in[6];
  const float* Wp_img  = (const float*)d_in[7];
  const float* bp_img  = (const float*)d_in[8];
  const float* Wp_rad  = (const float*)d_in[9];
  const float* bp_rad  = (const float*)d_in[10];
  float* out = (float*)d_out;

  // Workspace (66.1 MB total, under round-1's proven 75.5 MB footprint):
  //   Qh|Ql|Kh|Kl: [2][B][N][256] f16 (9.4 MB each)
  //   Vt:          [2][B][256][N] f16 (9.4 MB)
  //   A:           [2][B][N][256] f32 (18.9 MB)
  const size_t NE = (size_t)2 * NB * NSEQ * 256;   // 4,718,592
  f16* Qh = (f16*)d_ws;
  f16* Ql = Qh + NE;
  f16* Kh = Ql + NE;
  f16* Kl = Kh + NE;
  f16* Vt = Kl + NE;
  float* A = (float*)(Vt + NE);

  dim3 gp(12, 36, 2 * NB);
  proj_qkv<<<gp, 256, 0, stream>>>(img, rad, Wq_img, Wkv_img, Wq_rad, Wkv_rad,
                                   Qh, Ql, Kh, Kl, Vt);

  dim3 ga(NSEQ / 64, NB * NHEAD, 2);
  attn_mfma<<<ga, 256, 0, stream>>>(Qh, Ql, Kh, Kl, Vt, U, A);

  dim3 go(4, 36, 2 * NB);
  proj_out<<<go, 256, 0, stream>>>(A, Wp_img, bp_img, Wp_rad, bp_rad, out);
}

// Round 4
// 388.170 us; speedup vs baseline: 6.2705x; 1.2192x over previous
//
#include <hip/hip_runtime.h>
#include <math.h>

#define NB    4
#define CDIM  256
#define NSEQ  2304          // 48*48
#define NHEAD 8
#define HD    32
// SCALE * LOG2E folded into Q at projection time
#define QSCALE (0.17677669529663687f * 1.4426950408889634f)
#define INV2048 4.8828125e-4f

typedef _Float16 f16;
typedef _Float16 f16x8 __attribute__((ext_vector_type(8)));
typedef _Float16 f16x4 __attribute__((ext_vector_type(4)));
typedef float    f32x4 __attribute__((ext_vector_type(4)));

// ---------------------------------------------------------------------------
// Kernel 1: fused QKV projection, both modalities (z = mod*4+b), emitting
// f16 hi/lo splits directly.
//   Qh/Ql: [mod][b][n][256]  (QSCALE folded in; lo = (v-hi)*2048)
//   Kh/Kl: [mod][b][key][256]
//   Vt:    [mod][b][c=h*32+d][key]   (transposed, single f16)
// ---------------------------------------------------------------------------
__global__ __launch_bounds__(256) void proj_qkv(
    const float* __restrict__ X0, const float* __restrict__ X1,
    const float* __restrict__ Wq0, const float* __restrict__ Wkv0,
    const float* __restrict__ Wq1, const float* __restrict__ Wkv1,
    f16* __restrict__ Qh, f16* __restrict__ Ql,
    f16* __restrict__ Kh, f16* __restrict__ Kl, f16* __restrict__ Vt)
{
  __shared__ float As[16][64];
  __shared__ float Bs[16][64];
  const int zz = blockIdx.z;
  const int mod = zz >> 2, b = zz & 3;
  const int n0 = blockIdx.y * 64;
  const int j0 = blockIdx.x * 64;
  const int t  = threadIdx.x;
  const int tn = t & 15, tj = t >> 4;
  const int bn = mod * NB + b;

  const float* X   = mod ? X1  : X0;
  const float* Wq  = mod ? Wq1 : Wq0;
  const float* Wkv = mod ? Wkv1 : Wkv0;

  const float* Wsrc; int wld, jb;
  if (j0 < 256) { Wsrc = Wq;  wld = 256; jb = j0; }
  else          { Wsrc = Wkv; wld = 512; jb = j0 - 256; }

  const float* Xb = X + (size_t)b * CDIM * NSEQ;

  float acc[4][4];
#pragma unroll
  for (int i = 0; i < 4; ++i)
#pragma unroll
    for (int j = 0; j < 4; ++j) acc[i][j] = 0.f;

  const int akc = t >> 4;          // 0..15  (k row)
  const int ann = (t & 15) * 4;    // 0..60  (float4 col)

  for (int c0 = 0; c0 < CDIM; c0 += 16) {
    float4 av = *(const float4*)(Xb   + (size_t)(c0 + akc) * NSEQ + n0 + ann);
    float4 bv = *(const float4*)(Wsrc + (size_t)(c0 + akc) * wld  + jb + ann);
    *(float4*)&As[akc][ann] = av;
    *(float4*)&Bs[akc][ann] = bv;
    __syncthreads();
#pragma unroll
    for (int k = 0; k < 16; ++k) {
      float4 a = *(const float4*)&As[k][tn * 4];
      float4 w = *(const float4*)&Bs[k][tj * 4];
      float aa[4] = {a.x, a.y, a.z, a.w};
      float ww[4] = {w.x, w.y, w.z, w.w};
#pragma unroll
      for (int i = 0; i < 4; ++i)
#pragma unroll
        for (int j = 0; j < 4; ++j) acc[i][j] = fmaf(aa[i], ww[j], acc[i][j]);
    }
    __syncthreads();
  }

  if (j0 < 256) {
#pragma unroll
    for (int i = 0; i < 4; ++i) {
      int n = n0 + tn * 4 + i;
      f16x4 hv, lv;
#pragma unroll
      for (int j = 0; j < 4; ++j) {
        float v = acc[i][j] * QSCALE;
        f16 hh = (f16)v;
        hv[j] = hh;
        lv[j] = (f16)((v - (float)hh) * 2048.0f);
      }
      size_t off = ((size_t)bn * NSEQ + n) * 256 + j0 + tj * 4;
      *(f16x4*)(Qh + off) = hv;
      *(f16x4*)(Ql + off) = lv;
    }
  } else if (j0 < 512) {
#pragma unroll
    for (int i = 0; i < 4; ++i) {
      int n = n0 + tn * 4 + i;
      f16x4 hv, lv;
#pragma unroll
      for (int j = 0; j < 4; ++j) {
        float v = acc[i][j];
        f16 hh = (f16)v;
        hv[j] = hh;
        lv[j] = (f16)((v - (float)hh) * 2048.0f);
      }
      size_t off = ((size_t)bn * NSEQ + n) * 256 + (j0 - 256) + tj * 4;
      *(f16x4*)(Kh + off) = hv;
      *(f16x4*)(Kl + off) = lv;
    }
  } else {
#pragma unroll
    for (int j = 0; j < 4; ++j) {
      int jv = (j0 - 512) + tj * 4 + j;
      f16x4 hv;
#pragma unroll
      for (int i = 0; i < 4; ++i) hv[i] = (f16)acc[i][j];
      size_t off = ((size_t)bn * 256 + jv) * NSEQ + n0 + tn * 4;
      *(f16x4*)(Vt + off) = hv;
    }
  }
}

// ---------------------------------------------------------------------------
// Kernel 2: MFMA flash attention, S^T formulation, restructured for LDS pipe:
//  - 4 waves/block, each wave owns 32 q-rows (2 MFMA B-fragment groups);
//    K-fragments are read once per tile and consumed by both groups.
//  - P^T transform via per-wave LDS round-trip (4 ds_write_b64 +
//    4 ds_read_b128 per chunk) instead of 32 ds_bpermute.
//  - K tiles UNPADDED [64][32] (b128 fragment reads are dense-optimal;
//    padding caused R3's 4.25e7 bank-conflict cycles). V^T and P padded to
//    72 f16/row (dense for their access patterns).
//  - branch 1 (no uncertainty weight) uses single-f16 Q,K: 1 MFMA per S-tile,
//    no Kl staging.  branch 0 keeps the hi/lo split (3 MFMAs).
// ---------------------------------------------------------------------------
__global__ __launch_bounds__(256, 4) void attn_mfma(
    const f16* __restrict__ Qh, const f16* __restrict__ Ql,
    const f16* __restrict__ Kh, const f16* __restrict__ Kl,
    const f16* __restrict__ Vt, const float* __restrict__ U,
    float* __restrict__ A)
{
  __shared__ f16 KhS[64][32];      // unpadded: dense b128 banking
  __shared__ f16 KlS[64][32];
  __shared__ f16 VtS[32][72];      // 32 d x 64 keys, pad 64->72
  __shared__ f16 PS[4][32][72];    // per-wave P: 32 q-rows x 64 keys, pad 72

  const int branch = blockIdx.z;
  const int bh = blockIdx.y, b = bh >> 3, h = bh & 7;
  const int tid = threadIdx.x;
  const int wave = tid >> 6, lane = tid & 63;
  const int col = lane & 15, quad = lane >> 4;
  const int q0  = blockIdx.x * 128 + wave * 32;
  const int qr0 = q0 + col;          // group 0 q-row
  const int qr1 = q0 + 16 + col;     // group 1 q-row

  const int qmod = branch, kmod = 1 - branch;
  const size_t qbase = (size_t)(qmod * NB + b) * NSEQ * 256;
  const size_t kbase = (size_t)(kmod * NB + b) * NSEQ;
  const size_t vbase = (size_t)(kmod * NB + b) * 256;

  // Q B-fragments: B[k=d=quad*8+j][n=q=col]
  const f16x8 bqh0 = *(const f16x8*)(Qh + qbase + (size_t)qr0 * 256 + h * HD + quad * 8);
  const f16x8 bqh1 = *(const f16x8*)(Qh + qbase + (size_t)qr1 * 256 + h * HD + quad * 8);
  f16x8 bql0 = {}, bql1 = {};
  float uw0 = 1.0f, uw1 = 1.0f;
  if (branch == 0) {
    bql0 = *(const f16x8*)(Ql + qbase + (size_t)qr0 * 256 + h * HD + quad * 8);
    bql1 = *(const f16x8*)(Ql + qbase + (size_t)qr1 * 256 + h * HD + quad * 8);
    uw0 = 1.0f / (U[b * NSEQ + qr0] + 1e-6f);
    uw1 = 1.0f / (U[b * NSEQ + qr1] + 1e-6f);
  }

  float m0 = -1e30f, l0 = 0.f, m1 = -1e30f, l1 = 0.f;
  f32x4 oc00 = {0.f,0.f,0.f,0.f}, oc01 = {0.f,0.f,0.f,0.f};
  f32x4 oc10 = {0.f,0.f,0.f,0.f}, oc11 = {0.f,0.f,0.f,0.f};
  const f32x4 z4 = {0.f,0.f,0.f,0.f};

  for (int k0 = 0; k0 < NSEQ; k0 += 64) {
    __syncthreads();
    {
      // stage K (and Kl for branch 0) + V^T; one b128 per thread per tensor
      int row = tid >> 2, seg = tid & 3;
      size_t g = (kbase + k0 + row) * 256 + h * HD + seg * 8;
      *(f16x8*)&KhS[row][seg * 8] = *(const f16x8*)(Kh + g);
      if (branch == 0)
        *(f16x8*)&KlS[row][seg * 8] = *(const f16x8*)(Kl + g);
      int vrow = tid >> 3, vseg = tid & 7;
      size_t gv = (vbase + h * HD + vrow) * NSEQ + k0 + vseg * 8;
      *(f16x8*)&VtS[vrow][vseg * 8] = *(const f16x8*)(Vt + gv);
    }
    __syncthreads();

    // ---- S^T tiles: lane holds raw logits p[t*4+r] = key 16t+4*quad+r
    float p0[16], p1[16];
#pragma unroll
    for (int t = 0; t < 4; ++t) {
      f16x8 ah = *(const f16x8*)&KhS[t * 16 + col][quad * 8];
      f32x4 s0 = __builtin_amdgcn_mfma_f32_16x16x32_f16(ah, bqh0, z4, 0, 0, 0);
      f32x4 s1 = __builtin_amdgcn_mfma_f32_16x16x32_f16(ah, bqh1, z4, 0, 0, 0);
      if (branch == 0) {
        f16x8 al = *(const f16x8*)&KlS[t * 16 + col][quad * 8];
        f32x4 c0 = __builtin_amdgcn_mfma_f32_16x16x32_f16(ah, bql0, z4, 0, 0, 0);
        c0 = __builtin_amdgcn_mfma_f32_16x16x32_f16(al, bqh0, c0, 0, 0, 0);
        f32x4 c1 = __builtin_amdgcn_mfma_f32_16x16x32_f16(ah, bql1, z4, 0, 0, 0);
        c1 = __builtin_amdgcn_mfma_f32_16x16x32_f16(al, bqh1, c1, 0, 0, 0);
#pragma unroll
        for (int r = 0; r < 4; ++r) {
          p0[t * 4 + r] = fmaf(c0[r], INV2048, s0[r]);
          p1[t * 4 + r] = fmaf(c1[r], INV2048, s1[r]);
        }
      } else {
#pragma unroll
        for (int r = 0; r < 4; ++r) { p0[t * 4 + r] = s0[r]; p1[t * 4 + r] = s1[r]; }
      }
    }

    // ---- online softmax per group (uw folded into the exp-arg fma)
#pragma unroll
    for (int g = 0; g < 2; ++g) {
      float* p = g ? p1 : p0;
      const float uw = g ? uw1 : uw0;
      float& m = g ? m1 : m0;
      float& l = g ? l1 : l0;
      f32x4& oa = g ? oc10 : oc00;
      f32x4& ob = g ? oc11 : oc01;

      float r0 = fmaxf(fmaxf(p[0], p[1]),  fmaxf(p[2], p[3]));
      float r1 = fmaxf(fmaxf(p[4], p[5]),  fmaxf(p[6], p[7]));
      float r2 = fmaxf(fmaxf(p[8], p[9]),  fmaxf(p[10], p[11]));
      float r3 = fmaxf(fmaxf(p[12], p[13]), fmaxf(p[14], p[15]));
      float cmax = fmaxf(fmaxf(r0, r1), fmaxf(r2, r3)) * uw;   // scaled space
      cmax = fmaxf(cmax, __shfl_xor(cmax, 16, 64));
      cmax = fmaxf(cmax, __shfl_xor(cmax, 32, 64));
      const float mn = fmaxf(m, cmax);
      const float alpha = exp2f(m - mn);
      m = mn;
      float lsA = 0.f, lsB = 0.f;
#pragma unroll
      for (int i = 0; i < 16; i += 2) {
        float eA = exp2f(fmaf(p[i],     uw, -mn));
        float eB = exp2f(fmaf(p[i + 1], uw, -mn));
        p[i] = eA; p[i + 1] = eB;
        lsA += eA; lsB += eB;
      }
      float ls = lsA + lsB;
      ls += __shfl_xor(ls, 16, 64);
      ls += __shfl_xor(ls, 32, 64);
      l = fmaf(l, alpha, ls);
#pragma unroll
      for (int r = 0; r < 4; ++r) { oa[r] *= alpha; ob[r] *= alpha; }

      // write P rows [g*16+col] to per-wave LDS buffer (b64 per tile)
#pragma unroll
      for (int t = 0; t < 4; ++t) {
        f16x4 pk;
#pragma unroll
        for (int r = 0; r < 4; ++r) pk[r] = (f16)p[t * 4 + r];
        *(f16x4*)&PS[wave][g * 16 + col][t * 16 + quad * 4] = pk;
      }
    }

    // ---- PV: out^T[d][q] += V^T(32d x 32k) * P^T(32k x 16q) per group
#pragma unroll
    for (int s = 0; s < 2; ++s) {
      f16x8 av0 = *(const f16x8*)&VtS[col][s * 32 + quad * 8];
      f16x8 av1 = *(const f16x8*)&VtS[16 + col][s * 32 + quad * 8];
      f16x8 bp0 = *(const f16x8*)&PS[wave][col][s * 32 + quad * 8];
      f16x8 bp1 = *(const f16x8*)&PS[wave][16 + col][s * 32 + quad * 8];
      oc00 = __builtin_amdgcn_mfma_f32_16x16x32_f16(av0, bp0, oc00, 0, 0, 0);
      oc01 = __builtin_amdgcn_mfma_f32_16x16x32_f16(av1, bp0, oc01, 0, 0, 0);
      oc10 = __builtin_amdgcn_mfma_f32_16x16x32_f16(av0, bp1, oc10, 0, 0, 0);
      oc11 = __builtin_amdgcn_mfma_f32_16x16x32_f16(av1, bp1, oc11, 0, 0, 0);
    }
  }

  const float i0 = 1.0f / l0, i1 = 1.0f / l1;
  float* d0 = A + (((size_t)(branch * NB + b) * NSEQ) + qr0) * CDIM + h * HD;
  float* d1 = A + (((size_t)(branch * NB + b) * NSEQ) + qr1) * CDIM + h * HD;
#pragma unroll
  for (int r = 0; r < 4; ++r) {
    d0[quad * 4 + r]      = oc00[r] * i0;
    d0[16 + quad * 4 + r] = oc01[r] * i0;
    d1[quad * 4 + r]      = oc10[r] * i1;
    d1[16 + quad * 4 + r] = oc11[r] * i1;
  }
}

// ---------------------------------------------------------------------------
// Kernel 3: output projection + bias, both modalities (z = mod*4+b), writing
// (B, C, N) layout directly.  A: (mod, B, N, 256); O[mod][b, j, n].
// ---------------------------------------------------------------------------
__global__ __launch_bounds__(256) void proj_out(
    const float* __restrict__ A, const float* __restrict__ Wp0,
    const float* __restrict__ bp0, const float* __restrict__ Wp1,
    const float* __restrict__ bp1, float* __restrict__ O)
{
  __shared__ float As[16][68];
  __shared__ float Bs[16][64];
  const int zz = blockIdx.z;
  const int mod = zz >> 2, b = zz & 3;
  const int n0 = blockIdx.y * 64;
  const int j0 = blockIdx.x * 64;
  const int t  = threadIdx.x;
  const int tn = t & 15, tj = t >> 4;

  const float* Wp = mod ? Wp1 : Wp0;
  const float* bp = mod ? bp1 : bp0;
  const float* Ab = A + (size_t)(mod * NB + b) * NSEQ * CDIM;

  float acc[4][4];
#pragma unroll
  for (int i = 0; i < 4; ++i)
#pragma unroll
    for (int j = 0; j < 4; ++j) acc[i][j] = 0.f;

  const int ann = t >> 2;            // 0..63  (n within tile)
  const int akc = (t & 3) * 4;       // 0,4,8,12 (c chunk)
  const int bkc = t >> 4;            // 0..15
  const int bjj = (t & 15) * 4;      // 0..60

  for (int c0 = 0; c0 < CDIM; c0 += 16) {
    float4 av = *(const float4*)(Ab + (size_t)(n0 + ann) * CDIM + c0 + akc);
    float4 bv = *(const float4*)(Wp + (size_t)(c0 + bkc) * CDIM + j0 + bjj);
    As[akc + 0][ann] = av.x;
    As[akc + 1][ann] = av.y;
    As[akc + 2][ann] = av.z;
    As[akc + 3][ann] = av.w;
    *(float4*)&Bs[bkc][bjj] = bv;
    __syncthreads();
#pragma unroll
    for (int k = 0; k < 16; ++k) {
      float4 a = *(const float4*)&As[k][tn * 4];
      float4 w = *(const float4*)&Bs[k][tj * 4];
      float aa[4] = {a.x, a.y, a.z, a.w};
      float ww[4] = {w.x, w.y, w.z, w.w};
#pragma unroll
      for (int i = 0; i < 4; ++i)
#pragma unroll
        for (int j = 0; j < 4; ++j) acc[i][j] = fmaf(aa[i], ww[j], acc[i][j]);
    }
    __syncthreads();
  }

  float* Ob = O + (size_t)(mod * NB + b) * CDIM * NSEQ;
#pragma unroll
  for (int ji = 0; ji < 4; ++ji) {
    int j = j0 + tj * 4 + ji;
    float bias = bp[j];
    float4 v = make_float4(acc[0][ji] + bias, acc[1][ji] + bias,
                           acc[2][ji] + bias, acc[3][ji] + bias);
    *(float4*)(Ob + (size_t)j * NSEQ + n0 + tn * 4) = v;
  }
}

// ---------------------------------------------------------------------------
extern "C" void kernel_launch(void* const* d_in, const int* in_sizes, int n_in,
                              void* d_out, int out_size, void* d_ws, size_t ws_size,
                              hipStream_t stream) {
  (void)in_sizes; (void)n_in; (void)out_size; (void)ws_size;
  const float* img     = (const float*)d_in[0];
  const float* rad     = (const float*)d_in[1];
  const float* U       = (const float*)d_in[2];
  const float* Wq_img  = (const float*)d_in[3];
  const float* Wkv_rad = (const float*)d_in[4];
  const float* Wq_rad  = (const float*)d_in[5];
  const float* Wkv_img = (const float*)d_in[6];
  const float* Wp_img  = (const float*)d_in[7];
  const float* bp_img  = (const float*)d_in[8];
  const float* Wp_rad  = (const float*)d_in[9];
  const float* bp_rad  = (const float*)d_in[10];
  float* out = (float*)d_out;

  // Workspace (66.1 MB, unchanged from the proven R3 footprint):
  //   Qh|Ql|Kh|Kl: [2][B][N][256] f16;  Vt: [2][B][256][N] f16;
  //   A: [2][B][N][256] f32
  const size_t NE = (size_t)2 * NB * NSEQ * 256;   // 4,718,592
  f16* Qh = (f16*)d_ws;
  f16* Ql = Qh + NE;
  f16* Kh = Ql + NE;
  f16* Kl = Kh + NE;
  f16* Vt = Kl + NE;
  float* A = (float*)(Vt + NE);

  dim3 gp(12, 36, 2 * NB);
  proj_qkv<<<gp, 256, 0, stream>>>(img, rad, Wq_img, Wkv_img, Wq_rad, Wkv_rad,
                                   Qh, Ql, Kh, Kl, Vt);

  dim3 ga(NSEQ / 128, NB * NHEAD, 2);
  attn_mfma<<<ga, 256, 0, stream>>>(Qh, Ql, Kh, Kl, Vt, U, A);

  dim3 go(4, 36, 2 * NB);
  proj_out<<<go, 256, 0, stream>>>(A, Wp_img, bp_img, Wp_rad, bp_rad, out);
}